// Round 1
// 295.543 us; speedup vs baseline: 1.3504x; 1.3504x over previous
//
#include <hip/hip_runtime.h>

// B=2, C=4, D=64, H=256, W=256
// out = sum_{interior, keep} ||omega_p - omega_t||_2 / sum(keep)
// keep = all 27 masks in 3x3x3 neighborhood == 1; omega = neighbor diffs of
// (pred - targ) ch1..3 (SCALES=10 cancels 2*DELTA=10).
//
// R2 post-mortem: VGPR=60 forced the compiler to interleave waitcnt between
// load pairs -> serialized HBM latency. Fix (kept): issue ALL 29 float4
// loads into explicit register arrays BEFORE any consumption.
//
// R3 theory: dispatch time (204.7us) / atomic count (7936 blocks x 2 f64
// same-address RMWs = 15872) = 12.9ns = ~31 cy -> the kernel is serialized
// on L2 same-line atomic throughput, not memory BW (HBM 9.6%, VALU 7.9%,
// occupancy 30% all idle). Fix: spread block partials across 256 slot pairs
// (31 atomics/slot over ~64 distinct L2 lines), reduce slots in finalize.

#define SD 65536LL      // d stride = H*W
#define SC 4194304LL    // channel stride = D*H*W

__global__ __launch_bounds__(256) void vort_dense(
    const float* __restrict__ preds, const float* __restrict__ targs,
    const float* __restrict__ masks, double* __restrict__ acc, int slot_mask)
{
    const int lane = threadIdx.x & 63;
    const int wv   = threadIdx.x >> 6;
    int blk = blockIdx.x;
    const int tile = blk & 63; blk >>= 6;       // 64 h-tiles of 4 rows
    const int d = blk % 62 + 1; blk /= 62;      // interior d 1..62
    const int b = blk;                          // 0..1
    const int h = 1 + tile * 4 + wv;            // one row per wave
    const int w0 = lane << 2;                   // 4 w per lane, full 256 row

    float norm = 0.0f, cnt = 0.0f;

    if (h <= 254) {   // wave-uniform guard (tile 63 waves 2,3 out of range)
        const long long mbase = (long long)b * SC + (long long)d * SD
                              + (long long)h * 256 + w0;
        const long long b1 = ((long long)(b * 4 + 1) * 64 + d) * SD
                           + (long long)h * 256 + w0;
        const long long b2 = b1 + SC;
        const long long b3 = b2 + SC;

        // ---- issue ALL loads first: 10 pred + 10 targ + 9 mask float4 ----
        long long voff[10];
        voff[0] = b1 - SD;  voff[1] = b1 + SD;   // u d-/d+
        voff[2] = b1 - 256; voff[3] = b1 + 256;  // u h-/h+
        voff[4] = b2 - SD;  voff[5] = b2 + SD;   // v d-/d+
        voff[6] = b2;                             // v center
        voff[7] = b3 - 256; voff[8] = b3 + 256;  // w h-/h+
        voff[9] = b3;                             // w center

        float4 P[10], T[10], Mv[9];
        #pragma unroll
        for (int i = 0; i < 10; ++i) P[i] = *(const float4*)(preds + voff[i]);
        #pragma unroll
        for (int i = 0; i < 10; ++i) T[i] = *(const float4*)(targs + voff[i]);
        #pragma unroll
        for (int r = 0; r < 9; ++r) {
            const int dd = r / 3 - 1, dh = r % 3 - 1;
            Mv[r] = *(const float4*)(masks + mbase + (long long)dd * SD
                                     + (long long)dh * 256);
        }

        // ---- consume: diffs, mask min, shuffle edges, per-cell norm ----
        float Df[10][4];
        #pragma unroll
        for (int i = 0; i < 10; ++i) {
            Df[i][0] = P[i].x - T[i].x; Df[i][1] = P[i].y - T[i].y;
            Df[i][2] = P[i].z - T[i].z; Df[i][3] = P[i].w - T[i].w;
        }
        float4 M = Mv[0];
        #pragma unroll
        for (int r = 1; r < 9; ++r) {
            M.x = fminf(M.x, Mv[r].x); M.y = fminf(M.y, Mv[r].y);
            M.z = fminf(M.z, Mv[r].z); M.w = fminf(M.w, Mv[r].w);
        }

        const float vL = __shfl_up(Df[6][3], 1, 64);
        const float vR = __shfl_down(Df[6][0], 1, 64);
        const float wL = __shfl_up(Df[9][3], 1, 64);
        const float wR = __shfl_down(Df[9][0], 1, 64);
        const float ML = __shfl_up(M.w, 1, 64);
        const float MR = __shfl_down(M.x, 1, 64);

        const float vv[6] = { vL, Df[6][0], Df[6][1], Df[6][2], Df[6][3], vR };
        const float ww[6] = { wL, Df[9][0], Df[9][1], Df[9][2], Df[9][3], wR };
        const float Mm[6] = { ML, M.x, M.y, M.z, M.w, MR };

        #pragma unroll
        for (int j = 0; j < 4; ++j) {
            const int wc = w0 + j;
            const float keepv = fminf(fminf(Mm[j], Mm[j + 1]), Mm[j + 2]);
            const bool valid = (wc >= 1) && (wc <= 254) && (keepv > 0.5f);
            const float wx = (Df[8][j] - Df[7][j]) - (Df[5][j] - Df[4][j]);
            const float wy = (Df[1][j] - Df[0][j]) - (ww[j + 2] - ww[j]);
            const float wz = (vv[j + 2] - vv[j]) - (Df[3][j] - Df[2][j]);
            const float n = sqrtf(wx * wx + wy * wy + wz * wz);
            norm += valid ? n : 0.0f;
            cnt  += valid ? 1.0f : 0.0f;
        }
    }

    // ---- reduction: wave shuffle -> LDS across 4 waves -> spread atomic ----
    #pragma unroll
    for (int off = 32; off > 0; off >>= 1) {
        norm += __shfl_down(norm, off, 64);
        cnt  += __shfl_down(cnt,  off, 64);
    }
    __shared__ float ssum[4], scnt[4];
    if (lane == 0) { ssum[wv] = norm; scnt[wv] = cnt; }
    __syncthreads();
    if (threadIdx.x == 0) {
        const float s = ssum[0] + ssum[1] + ssum[2] + ssum[3];
        const float c = scnt[0] + scnt[1] + scnt[2] + scnt[3];
        double* slot = acc + 2 * (blockIdx.x & slot_mask);
        atomicAdd(&slot[0], (double)s);
        atomicAdd(&slot[1], (double)c);
    }
}

__global__ __launch_bounds__(256) void finalize_kernel(
    const double* __restrict__ acc, float* __restrict__ out, int nslots)
{
    const int lane = threadIdx.x & 63;
    const int wv   = threadIdx.x >> 6;
    double s = 0.0, c = 0.0;
    for (int i = threadIdx.x; i < nslots; i += 256) {
        s += acc[2 * i];
        c += acc[2 * i + 1];
    }
    #pragma unroll
    for (int off = 32; off > 0; off >>= 1) {
        s += __shfl_down(s, off, 64);
        c += __shfl_down(c, off, 64);
    }
    __shared__ double ss[4], sc[4];
    if (lane == 0) { ss[wv] = s; sc[wv] = c; }
    __syncthreads();
    if (threadIdx.x == 0) {
        const double S = ss[0] + ss[1] + ss[2] + ss[3];
        const double C = sc[0] + sc[1] + sc[2] + sc[3];
        out[0] = (C != 0.0) ? (float)(S / C) : 0.0f;
    }
}

extern "C" void kernel_launch(void* const* d_in, const int* in_sizes, int n_in,
                              void* d_out, int out_size, void* d_ws, size_t ws_size,
                              hipStream_t stream)
{
    const float* preds = (const float*)d_in[0];
    const float* targs = (const float*)d_in[1];
    const float* masks = (const float*)d_in[2];
    float* out = (float*)d_out;
    double* acc = (double*)d_ws;

    // 256 slot pairs (4 KB); fall back to fewer if workspace is tiny.
    int nslots = 256;
    while ((size_t)nslots * 2 * sizeof(double) > ws_size && nslots > 1)
        nslots >>= 1;

    hipMemsetAsync(d_ws, 0, (size_t)nslots * 2 * sizeof(double), stream);

    const int nblocks = 2 * 62 * 64;   // (b, d-1, h-tile)
    vort_dense<<<nblocks, 256, 0, stream>>>(preds, targs, masks, acc,
                                            nslots - 1);
    finalize_kernel<<<1, 256, 0, stream>>>(acc, out, nslots);
}

// Round 2
// 286.784 us; speedup vs baseline: 1.3917x; 1.0305x over previous
//
#include <hip/hip_runtime.h>

// B=2, C=4, D=64, H=256, W=256
// out = sum_{interior, keep} ||omega_p - omega_t||_2 / sum(keep)
// keep = all 27 masks in 3x3x3 neighborhood == 1; omega = neighbor diffs of
// (pred - targ) ch1..3 (SCALES=10 cancels 2*DELTA=10).
//
// R3 post-mortem: spreading atomics over 256 slots removed ~109us of L2
// same-line RMW serialization (204.7 -> 95.7us). Remaining: all pipes idle
// (HBM 20%, VALU 16%) -> per-wave load-latency batches. L2-traffic floor is
// ~27us (943MB @ 34.5TB/s).
//
// R4: d-march coarsening. Each wave owns one h-row and marches 4 d-slices,
// rolling u/v center-row diffs and per-plane mask h-mins in registers.
// Fresh loads per step: 7 pred + 7 targ + 3 mask = 17 float4 (vs 29).
// Mask reuse 9->3 is the main cut. Blocks 7936 -> 2048, waves live 4x
// longer -> loop-level pipelining of loads against compute.

#define SD 65536LL      // d stride = H*W
#define SC 4194304LL    // channel stride = D*H*W (== mask batch stride)

__device__ __forceinline__ float4 sub4(float4 a, float4 b) {
    return make_float4(a.x - b.x, a.y - b.y, a.z - b.z, a.w - b.w);
}
__device__ __forceinline__ float4 min4(float4 a, float4 b) {
    return make_float4(fminf(a.x, b.x), fminf(a.y, b.y),
                       fminf(a.z, b.z), fminf(a.w, b.w));
}
#define C4(v, j) ((j) == 0 ? (v).x : (j) == 1 ? (v).y : (j) == 2 ? (v).z : (v).w)

__global__ __launch_bounds__(256) void vort_march(
    const float* __restrict__ preds, const float* __restrict__ targs,
    const float* __restrict__ masks, double* __restrict__ acc, int slot_mask)
{
    const int lane = threadIdx.x & 63;
    const int wv   = threadIdx.x >> 6;
    int blk = blockIdx.x;
    const int tile = blk & 63; blk >>= 6;       // 64 h-tiles of 4 rows
    const int c    = blk & 15; blk >>= 4;       // 16 d-chunks
    const int b    = blk;                       // 0..1
    const int d0   = 1 + 4 * c;                 // chunk covers d0..d0+nstep-1
    const int nstep = (c < 15) ? 4 : 2;         // d interior 1..62
    const int h = 1 + tile * 4 + wv;            // one row per wave
    const int w0 = lane << 2;                   // 4 w per lane, full 256 row

    float norm = 0.0f, cnt = 0.0f;

    if (h <= 254) {   // wave-uniform guard
        const long long rowhw = (long long)h * 256 + w0;
        const long long mrow  = (long long)b * SC + (long long)d0 * SD + rowhw;
        const long long urow  = ((long long)(b * 4 + 1) * 64 + d0) * SD + rowhw;
        const long long vrow  = urow + SC;
        const long long wrow  = vrow + SC;

        // ---- prologue: planes d0-1, d0 (issue all 14 loads, then consume) --
        float4 Pu0 = *(const float4*)(preds + urow - SD);
        float4 Pu1 = *(const float4*)(preds + urow);
        float4 Pv0 = *(const float4*)(preds + vrow - SD);
        float4 Pv1 = *(const float4*)(preds + vrow);
        float4 Tu0 = *(const float4*)(targs + urow - SD);
        float4 Tu1 = *(const float4*)(targs + urow);
        float4 Tv0 = *(const float4*)(targs + vrow - SD);
        float4 Tv1 = *(const float4*)(targs + vrow);
        float4 Ma0 = *(const float4*)(masks + mrow - SD - 256);
        float4 Mb0 = *(const float4*)(masks + mrow - SD);
        float4 Mc0 = *(const float4*)(masks + mrow - SD + 256);
        float4 Ma1 = *(const float4*)(masks + mrow - 256);
        float4 Mb1 = *(const float4*)(masks + mrow);
        float4 Mc1 = *(const float4*)(masks + mrow + 256);

        // rolling state: u/v center-row diffs at d-1,d ; mask plane h-mins
        float4 cu0 = sub4(Pu0, Tu0), cu1 = sub4(Pu1, Tu1);
        float4 cv0 = sub4(Pv0, Tv0), cv1 = sub4(Pv1, Tv1);
        float4 m0  = min4(Ma0, min4(Mb0, Mc0));
        float4 m1  = min4(Ma1, min4(Mb1, Mc1));

        for (int s = 0; s < nstep; ++s) {
            const long long o = (long long)s * SD;

            // ---- issue all 17 fresh loads first ----
            float4 PuN  = *(const float4*)(preds + urow + o + SD);
            float4 Puhm = *(const float4*)(preds + urow + o - 256);
            float4 Puhp = *(const float4*)(preds + urow + o + 256);
            float4 PvN  = *(const float4*)(preds + vrow + o + SD);
            float4 Pwm  = *(const float4*)(preds + wrow + o - 256);
            float4 Pwc  = *(const float4*)(preds + wrow + o);
            float4 Pwp  = *(const float4*)(preds + wrow + o + 256);
            float4 TuN  = *(const float4*)(targs + urow + o + SD);
            float4 Tuhm = *(const float4*)(targs + urow + o - 256);
            float4 Tuhp = *(const float4*)(targs + urow + o + 256);
            float4 TvN  = *(const float4*)(targs + vrow + o + SD);
            float4 Twm  = *(const float4*)(targs + wrow + o - 256);
            float4 Twc  = *(const float4*)(targs + wrow + o);
            float4 Twp  = *(const float4*)(targs + wrow + o + 256);
            float4 MaN  = *(const float4*)(masks + mrow + o + SD - 256);
            float4 MbN  = *(const float4*)(masks + mrow + o + SD);
            float4 McN  = *(const float4*)(masks + mrow + o + SD + 256);

            // ---- consume ----
            float4 cu2 = sub4(PuN, TuN);            // u(d+1,h)
            float4 uhm = sub4(Puhm, Tuhm);          // u(d,h-1)
            float4 uhp = sub4(Puhp, Tuhp);          // u(d,h+1)
            float4 cv2 = sub4(PvN, TvN);            // v(d+1,h)
            float4 wm  = sub4(Pwm, Twm);            // w(d,h-1)
            float4 wc4 = sub4(Pwc, Twc);            // w(d,h)
            float4 wp  = sub4(Pwp, Twp);            // w(d,h+1)
            float4 m2  = min4(MaN, min4(MbN, McN)); // mask plane d+1 h-min
            float4 keep4 = min4(m0, min4(m1, m2));  // 3x3 d,h mask min

            const float vLs = __shfl_up(cv1.w, 1, 64);
            const float vRs = __shfl_down(cv1.x, 1, 64);
            const float wLs = __shfl_up(wc4.w, 1, 64);
            const float wRs = __shfl_down(wc4.x, 1, 64);
            const float kLs = __shfl_up(keep4.w, 1, 64);
            const float kRs = __shfl_down(keep4.x, 1, 64);

            const float vv[6] = { vLs, cv1.x, cv1.y, cv1.z, cv1.w, vRs };
            const float ww[6] = { wLs, wc4.x, wc4.y, wc4.z, wc4.w, wRs };
            const float kk[6] = { kLs, keep4.x, keep4.y, keep4.z, keep4.w, kRs };

            #pragma unroll
            for (int j = 0; j < 4; ++j) {
                const int wcI = w0 + j;
                const float keep = fminf(fminf(kk[j], kk[j + 1]), kk[j + 2]);
                const bool valid = (wcI >= 1) && (wcI <= 254) && (keep > 0.5f);
                const float wx = (C4(wp, j) - C4(wm, j)) - (C4(cv2, j) - C4(cv0, j));
                const float wy = (C4(cu2, j) - C4(cu0, j)) - (ww[j + 2] - ww[j]);
                const float wz = (vv[j + 2] - vv[j]) - (C4(uhp, j) - C4(uhm, j));
                const float n = sqrtf(wx * wx + wy * wy + wz * wz);
                norm += valid ? n : 0.0f;
                cnt  += valid ? 1.0f : 0.0f;
            }

            // rotate rolling windows
            cu0 = cu1; cu1 = cu2;
            cv0 = cv1; cv1 = cv2;
            m0  = m1;  m1  = m2;
        }
    }

    // ---- reduction: wave shuffle -> LDS across 4 waves -> spread atomic ----
    #pragma unroll
    for (int off = 32; off > 0; off >>= 1) {
        norm += __shfl_down(norm, off, 64);
        cnt  += __shfl_down(cnt,  off, 64);
    }
    __shared__ float ssum[4], scnt[4];
    if (lane == 0) { ssum[wv] = norm; scnt[wv] = cnt; }
    __syncthreads();
    if (threadIdx.x == 0) {
        const float s = ssum[0] + ssum[1] + ssum[2] + ssum[3];
        const float c2 = scnt[0] + scnt[1] + scnt[2] + scnt[3];
        double* slot = acc + 2 * (blockIdx.x & slot_mask);
        atomicAdd(&slot[0], (double)s);
        atomicAdd(&slot[1], (double)c2);
    }
}

__global__ __launch_bounds__(256) void finalize_kernel(
    const double* __restrict__ acc, float* __restrict__ out, int nslots)
{
    const int lane = threadIdx.x & 63;
    const int wv   = threadIdx.x >> 6;
    double s = 0.0, c = 0.0;
    for (int i = threadIdx.x; i < nslots; i += 256) {
        s += acc[2 * i];
        c += acc[2 * i + 1];
    }
    #pragma unroll
    for (int off = 32; off > 0; off >>= 1) {
        s += __shfl_down(s, off, 64);
        c += __shfl_down(c, off, 64);
    }
    __shared__ double ss[4], sc[4];
    if (lane == 0) { ss[wv] = s; sc[wv] = c; }
    __syncthreads();
    if (threadIdx.x == 0) {
        const double S = ss[0] + ss[1] + ss[2] + ss[3];
        const double C = sc[0] + sc[1] + sc[2] + sc[3];
        out[0] = (C != 0.0) ? (float)(S / C) : 0.0f;
    }
}

extern "C" void kernel_launch(void* const* d_in, const int* in_sizes, int n_in,
                              void* d_out, int out_size, void* d_ws, size_t ws_size,
                              hipStream_t stream)
{
    const float* preds = (const float*)d_in[0];
    const float* targs = (const float*)d_in[1];
    const float* masks = (const float*)d_in[2];
    float* out = (float*)d_out;
    double* acc = (double*)d_ws;

    // 256 slot pairs (4 KB); fall back to fewer if workspace is tiny.
    int nslots = 256;
    while ((size_t)nslots * 2 * sizeof(double) > ws_size && nslots > 1)
        nslots >>= 1;

    hipMemsetAsync(d_ws, 0, (size_t)nslots * 2 * sizeof(double), stream);

    const int nblocks = 2 * 16 * 64;   // (b, d-chunk, h-tile)
    vort_march<<<nblocks, 256, 0, stream>>>(preds, targs, masks, acc,
                                            nslots - 1);
    finalize_kernel<<<1, 256, 0, stream>>>(acc, out, nslots);
}